// Round 5
// baseline (427.487 us; speedup 1.0000x reference)
//
#include <hip/hip_runtime.h>

// out = 1 - (1/B) * sum_c || sum_{b: label_b=c} x_b/||x_b|| ||
// Pipeline: label count -> class-offset scan -> atomic-cursor permutation
// (within-class order nondeterministic; fp reorder error ~1e-6 << 1.9e-2
// threshold) -> streaming segmented sum over class-sorted rows -> norms.

#define DIM 256       // feature dim (fixed by problem setup)
#define NBC 256       // count / permute blocks
#define SSB 2048      // segmented-sum blocks: 8192 waves = full occupancy

typedef float fx4 __attribute__((ext_vector_type(4)));

// ---------------------------------------------------------------------------
// K1: global label histogram (LDS-privatized, int4 label loads); also zeroes
// the sums table so no extra memset dispatch is needed. cnt[] pre-zeroed by
// the one hipMemsetAsync in kernel_launch.
// ---------------------------------------------------------------------------
__global__ __launch_bounds__(256) void k_count(const int4* __restrict__ labels4,
                                               int* __restrict__ cnt,
                                               float* __restrict__ sums,
                                               int B4, int C, int CD) {
  __shared__ int s_h[1024];
  const int tid = threadIdx.x;
  const int gid = blockIdx.x * 256 + tid;
  for (int i = gid; i < CD; i += NBC * 256) sums[i] = 0.f;
  for (int c = tid; c < 1024; c += 256) s_h[c] = 0;
  __syncthreads();
  for (int i = gid; i < B4; i += NBC * 256) {
    const int4 L = labels4[i];
    atomicAdd(&s_h[L.x], 1);
    atomicAdd(&s_h[L.y], 1);
    atomicAdd(&s_h[L.z], 1);
    atomicAdd(&s_h[L.w], 1);
  }
  __syncthreads();
  for (int c = tid; c < C; c += 256) {
    const int v = s_h[c];
    if (v) atomicAdd(&cnt[c], v);
  }
}

// ---------------------------------------------------------------------------
// K2: single block: exclusive scan of cnt -> class offsets -> cursors.
// Also zeroes out[0] before k_norm's atomics.
// ---------------------------------------------------------------------------
__global__ __launch_bounds__(1024) void k_scan(const int* __restrict__ cnt,
                                               int* __restrict__ cursors,
                                               float* __restrict__ out, int C) {
  __shared__ int s[2][1024];
  const int tid = threadIdx.x;
  if (tid == 0) out[0] = 0.f;
  const int total = (tid < C) ? cnt[tid] : 0;
  int cur = 0;
  s[0][tid] = total;
  __syncthreads();
  for (int d = 1; d < 1024; d <<= 1) {  // Hillis-Steele inclusive scan
    const int v = s[cur][tid] + (tid >= d ? s[cur][tid - d] : 0);
    s[1 - cur][tid] = v;
    __syncthreads();
    cur ^= 1;
  }
  if (tid < C) cursors[tid] = s[cur][tid] - total;  // exclusive offset
}

// ---------------------------------------------------------------------------
// K3: permutation via global atomic cursors (1000 L2-resident addresses,
// ~262 ops each — microseconds). Within-class order nondeterministic: fine.
// ---------------------------------------------------------------------------
__global__ __launch_bounds__(256) void k_permute(const int* __restrict__ labels,
                                                 int* __restrict__ cursors,
                                                 int2* __restrict__ pr, int B) {
  const int gid = blockIdx.x * 256 + threadIdx.x;
  for (int i = gid; i < B; i += NBC * 256) {
    const int l = labels[i];
    const int pos = atomicAdd(&cursors[l], 1);
    pr[pos] = make_int2(i, l);
  }
}

// ---------------------------------------------------------------------------
// K4: streaming segmented sum over class-sorted rows. 8192 waves, 32 rows
// each, batches of 8 so 8 independent 1KB row loads are in flight per wave.
// pr entries are wave-uniform scalar loads.
// ---------------------------------------------------------------------------
__device__ __forceinline__ void flush_acc(float* __restrict__ sums, int c,
                                          const fx4& a, int lane) {
  float* dst = sums + (size_t)c * DIM + lane * 4;
  atomicAdd(dst + 0, a.x);
  atomicAdd(dst + 1, a.y);
  atomicAdd(dst + 2, a.z);
  atomicAdd(dst + 3, a.w);
}

__global__ __launch_bounds__(256) void k_segsum(const float* __restrict__ x,
                                                const int2* __restrict__ pr,
                                                float* __restrict__ sums,
                                                int B) {
  const int lane = threadIdx.x & 63;
  const int wid = __builtin_amdgcn_readfirstlane(
      (blockIdx.x << 2) | (threadIdx.x >> 6));
  const int nw = SSB * 4;
  const int per = (B + nw - 1) / nw;  // 32 for B=262144
  const int r0 = wid * per;
  const int r1 = min(B, r0 + per);
  if (r0 >= r1) return;

  fx4 acc = {0.f, 0.f, 0.f, 0.f};
  int prev = -1;
  int rb = r0;

  for (; rb + 8 <= r1; rb += 8) {
    int2 e[8];
#pragma unroll
    for (int k = 0; k < 8; ++k) e[k] = pr[rb + k];  // uniform -> s_load
    fx4 v[8];
#pragma unroll
    for (int k = 0; k < 8; ++k)  // 8 independent 1KB coalesced loads
      v[k] = __builtin_nontemporal_load(
          (const fx4*)(x + (size_t)e[k].x * DIM) + lane);
    float ss[8];
#pragma unroll
    for (int k = 0; k < 8; ++k)
      ss[k] = v[k].x * v[k].x + v[k].y * v[k].y + v[k].z * v[k].z +
              v[k].w * v[k].w;
#pragma unroll
    for (int off = 32; off; off >>= 1) {  // 8 interleaved reduce chains
#pragma unroll
      for (int k = 0; k < 8; ++k) ss[k] += __shfl_xor(ss[k], off);
    }
#pragma unroll
    for (int k = 0; k < 8; ++k) {
      const float inv = 1.f / fmaxf(sqrtf(ss[k]), 1e-12f);
      const int lab = e[k].y;
      if (lab != prev) {  // wave-uniform (scalar) branch
        if (prev >= 0) flush_acc(sums, prev, acc, lane);
        acc = (fx4){0.f, 0.f, 0.f, 0.f};
        prev = lab;
      }
      acc.x += v[k].x * inv; acc.y += v[k].y * inv;
      acc.z += v[k].z * inv; acc.w += v[k].w * inv;
    }
  }
  for (; rb < r1; ++rb) {  // tail (unused when per % 8 == 0)
    const int2 e = pr[rb];
    const fx4 v = ((const fx4*)(x + (size_t)e.x * DIM))[lane];
    float ss = v.x * v.x + v.y * v.y + v.z * v.z + v.w * v.w;
#pragma unroll
    for (int off = 32; off; off >>= 1) ss += __shfl_xor(ss, off);
    const float inv = 1.f / fmaxf(sqrtf(ss), 1e-12f);
    if (e.y != prev) {
      if (prev >= 0) flush_acc(sums, prev, acc, lane);
      acc = (fx4){0.f, 0.f, 0.f, 0.f};
      prev = e.y;
    }
    acc.x += v.x * inv; acc.y += v.y * inv;
    acc.z += v.z * inv; acc.w += v.w * inv;
  }
  if (prev >= 0) flush_acc(sums, prev, acc, lane);
}

// ---------------------------------------------------------------------------
// K5: per-class norm, block-sum, one atomic per block into out[0]; the last
// block to finish (done-counter) applies the final 1 - T/B transform.
// ---------------------------------------------------------------------------
__global__ __launch_bounds__(256) void k_norm(const float* __restrict__ sums,
                                              float* __restrict__ out,
                                              unsigned* __restrict__ done,
                                              int C, int B) {
  const int wave = threadIdx.x >> 6;
  const int lane = threadIdx.x & 63;
  const int c = blockIdx.x * 4 + wave;
  float term = 0.f;
  if (c < C) {
    const fx4 v = ((const fx4*)(sums + (size_t)c * DIM))[lane];
    float ss = v.x * v.x + v.y * v.y + v.z * v.z + v.w * v.w;
#pragma unroll
    for (int off = 32; off; off >>= 1) ss += __shfl_xor(ss, off);
    term = sqrtf(ss);  // 0 for empty classes, matching reference
  }
  __shared__ float sp[4];
  if (lane == 0) sp[wave] = term;
  __syncthreads();
  if (threadIdx.x == 0) {
    atomicAdd(out, sp[0] + sp[1] + sp[2] + sp[3]);
    __threadfence();  // out-add visible before done-add
    const unsigned d = atomicAdd(done, 1u);
    if (d == gridDim.x - 1) {           // all other blocks' adds are visible
      const float t = atomicAdd(out, 0.f);  // device-coherent read of total
      out[0] = 1.f - t / (float)B;
    }
  }
}

extern "C" void kernel_launch(void* const* d_in, const int* in_sizes, int n_in,
                              void* d_out, int out_size, void* d_ws, size_t ws_size,
                              hipStream_t stream) {
  const float* x      = (const float*)d_in[0];
  const int*   labels = (const int*)d_in[1];
  const int B = in_sizes[1];
  const int C = 1000;  // fixed by problem setup

  // ws layout: cnt[C] | done | cursors[C] | pr[B] int2 | sums[C*DIM] floats
  char* ws = (char*)d_ws;
  int*      cnt     = (int*)ws;
  unsigned* done    = (unsigned*)(ws + (size_t)C * sizeof(int));
  int*      cursors = (int*)(ws + (size_t)(C + 1) * sizeof(int));
  size_t off = (((size_t)(2 * C + 1) * sizeof(int)) + 15) & ~(size_t)15;
  int2*  pr   = (int2*)(ws + off);
  off += (size_t)B * sizeof(int2);
  float* sums = (float*)(ws + off);

  // one memset covers cnt[C] + done (ws is poisoned 0xAA before every call)
  hipMemsetAsync(cnt, 0, (size_t)(C + 1) * sizeof(int), stream);

  k_count<<<NBC, 256, 0, stream>>>((const int4*)labels, cnt, sums, B / 4, C,
                                   C * DIM);
  k_scan<<<1, 1024, 0, stream>>>(cnt, cursors, (float*)d_out, C);
  k_permute<<<NBC, 256, 0, stream>>>(labels, cursors, pr, B);
  k_segsum<<<SSB, 256, 0, stream>>>(x, pr, sums, B);
  const int nblk = (C + 3) / 4;
  k_norm<<<nblk, 256, 0, stream>>>(sums, (float*)d_out, done, C, B);
}

// Round 6
// 425.931 us; speedup vs baseline: 1.0037x; 1.0037x over previous
//
#include <hip/hip_runtime.h>

// out = 1 - (1/B) * sum_c || sum_{b: label_b=c} x_b/||x_b|| ||
// Pipeline: init -> label count -> class-offset scan -> atomic-cursor
// permutation (within-class order nondeterministic; fp reorder error ~1e-6,
// measured absmax 0.0) -> streaming segmented sum over class-sorted rows ->
// per-class norms + fused final transform. No memset nodes (a tiny fill node
// cost 171us in round 5's graph).

#define DIM 256       // feature dim (fixed by problem setup)
#define NBC 256       // count / permute blocks
#define SSB 2048      // segmented-sum blocks: 8192 waves = full occupancy

typedef float fx4 __attribute__((ext_vector_type(4)));

// ---------------------------------------------------------------------------
// K0: zero cnt[C] and done (replaces hipMemsetAsync graph fill node)
// ---------------------------------------------------------------------------
__global__ __launch_bounds__(512) void k_init(int* __restrict__ cnt, int C) {
  const int i = blockIdx.x * 512 + threadIdx.x;
  if (i <= C) cnt[i] = 0;  // cnt[C] doubles as the done counter
}

// ---------------------------------------------------------------------------
// K1: global label histogram (LDS-privatized, int4 label loads); also zeroes
// the sums table so no extra dispatch is needed.
// ---------------------------------------------------------------------------
__global__ __launch_bounds__(256) void k_count(const int4* __restrict__ labels4,
                                               int* __restrict__ cnt,
                                               float* __restrict__ sums,
                                               int B4, int C, int CD) {
  __shared__ int s_h[1024];
  const int tid = threadIdx.x;
  const int gid = blockIdx.x * 256 + tid;
  for (int i = gid; i < CD; i += NBC * 256) sums[i] = 0.f;
  for (int c = tid; c < 1024; c += 256) s_h[c] = 0;
  __syncthreads();
  for (int i = gid; i < B4; i += NBC * 256) {
    const int4 L = labels4[i];
    atomicAdd(&s_h[L.x], 1);
    atomicAdd(&s_h[L.y], 1);
    atomicAdd(&s_h[L.z], 1);
    atomicAdd(&s_h[L.w], 1);
  }
  __syncthreads();
  for (int c = tid; c < C; c += 256) {
    const int v = s_h[c];
    if (v) atomicAdd(&cnt[c], v);
  }
}

// ---------------------------------------------------------------------------
// K2: single block: exclusive scan of cnt -> class-offset cursors.
// Also zeroes out[0] before k_norm's atomics.
// ---------------------------------------------------------------------------
__global__ __launch_bounds__(1024) void k_scan(const int* __restrict__ cnt,
                                               int* __restrict__ cursors,
                                               float* __restrict__ out, int C) {
  __shared__ int s[2][1024];
  const int tid = threadIdx.x;
  if (tid == 0) out[0] = 0.f;
  const int total = (tid < C) ? cnt[tid] : 0;
  int cur = 0;
  s[0][tid] = total;
  __syncthreads();
  for (int d = 1; d < 1024; d <<= 1) {  // Hillis-Steele inclusive scan
    const int v = s[cur][tid] + (tid >= d ? s[cur][tid - d] : 0);
    s[1 - cur][tid] = v;
    __syncthreads();
    cur ^= 1;
  }
  if (tid < C) cursors[tid] = s[cur][tid] - total;  // exclusive offset
}

// ---------------------------------------------------------------------------
// K3: permutation via global atomic cursors (1000 L2-resident addresses,
// ~262 ops each). Within-class order nondeterministic: fine (absmax 0.0).
// ---------------------------------------------------------------------------
__global__ __launch_bounds__(256) void k_permute(const int* __restrict__ labels,
                                                 int* __restrict__ cursors,
                                                 int2* __restrict__ pr, int B) {
  const int gid = blockIdx.x * 256 + threadIdx.x;
  for (int i = gid; i < B; i += NBC * 256) {
    const int l = labels[i];
    const int pos = atomicAdd(&cursors[l], 1);
    pr[pos] = make_int2(i, l);
  }
}

// ---------------------------------------------------------------------------
// K4: streaming segmented sum over class-sorted rows. 8192 waves, 32 rows
// each, batches of 8 so 8 independent 1KB row loads are in flight per wave.
// ---------------------------------------------------------------------------
__device__ __forceinline__ void flush_acc(float* __restrict__ sums, int c,
                                          const fx4& a, int lane) {
  float* dst = sums + (size_t)c * DIM + lane * 4;
  atomicAdd(dst + 0, a.x);
  atomicAdd(dst + 1, a.y);
  atomicAdd(dst + 2, a.z);
  atomicAdd(dst + 3, a.w);
}

__global__ __launch_bounds__(256) void k_segsum(const float* __restrict__ x,
                                                const int2* __restrict__ pr,
                                                float* __restrict__ sums,
                                                int B) {
  const int lane = threadIdx.x & 63;
  const int wid = __builtin_amdgcn_readfirstlane(
      (blockIdx.x << 2) | (threadIdx.x >> 6));
  const int nw = SSB * 4;
  const int per = (B + nw - 1) / nw;  // 32 for B=262144
  const int r0 = wid * per;
  const int r1 = min(B, r0 + per);
  if (r0 >= r1) return;

  fx4 acc = {0.f, 0.f, 0.f, 0.f};
  int prev = -1;
  int rb = r0;

  for (; rb + 8 <= r1; rb += 8) {
    int2 e[8];
#pragma unroll
    for (int k = 0; k < 8; ++k) e[k] = pr[rb + k];  // wave-uniform
    fx4 v[8];
#pragma unroll
    for (int k = 0; k < 8; ++k)  // 8 independent 1KB coalesced loads
      v[k] = __builtin_nontemporal_load(
          (const fx4*)(x + (size_t)e[k].x * DIM) + lane);
    float ss[8];
#pragma unroll
    for (int k = 0; k < 8; ++k)
      ss[k] = v[k].x * v[k].x + v[k].y * v[k].y + v[k].z * v[k].z +
              v[k].w * v[k].w;
#pragma unroll
    for (int off = 32; off; off >>= 1) {  // 8 interleaved reduce chains
#pragma unroll
      for (int k = 0; k < 8; ++k) ss[k] += __shfl_xor(ss[k], off);
    }
#pragma unroll
    for (int k = 0; k < 8; ++k) {
      const float inv = 1.f / fmaxf(sqrtf(ss[k]), 1e-12f);
      const int lab = e[k].y;
      if (lab != prev) {  // wave-uniform (scalar) branch
        if (prev >= 0) flush_acc(sums, prev, acc, lane);
        acc = (fx4){0.f, 0.f, 0.f, 0.f};
        prev = lab;
      }
      acc.x += v[k].x * inv; acc.y += v[k].y * inv;
      acc.z += v[k].z * inv; acc.w += v[k].w * inv;
    }
  }
  for (; rb < r1; ++rb) {  // tail (unused when per % 8 == 0)
    const int2 e = pr[rb];
    const fx4 v = ((const fx4*)(x + (size_t)e.x * DIM))[lane];
    float ss = v.x * v.x + v.y * v.y + v.z * v.z + v.w * v.w;
#pragma unroll
    for (int off = 32; off; off >>= 1) ss += __shfl_xor(ss, off);
    const float inv = 1.f / fmaxf(sqrtf(ss), 1e-12f);
    if (e.y != prev) {
      if (prev >= 0) flush_acc(sums, prev, acc, lane);
      acc = (fx4){0.f, 0.f, 0.f, 0.f};
      prev = e.y;
    }
    acc.x += v.x * inv; acc.y += v.y * inv;
    acc.z += v.z * inv; acc.w += v.w * inv;
  }
  if (prev >= 0) flush_acc(sums, prev, acc, lane);
}

// ---------------------------------------------------------------------------
// K5: per-class norm, block-sum, one atomic per block into out[0]; the last
// block to finish (done-counter) applies the final 1 - T/B transform.
// ---------------------------------------------------------------------------
__global__ __launch_bounds__(256) void k_norm(const float* __restrict__ sums,
                                              float* __restrict__ out,
                                              unsigned* __restrict__ done,
                                              int C, int B) {
  const int wave = threadIdx.x >> 6;
  const int lane = threadIdx.x & 63;
  const int c = blockIdx.x * 4 + wave;
  float term = 0.f;
  if (c < C) {
    const fx4 v = ((const fx4*)(sums + (size_t)c * DIM))[lane];
    float ss = v.x * v.x + v.y * v.y + v.z * v.z + v.w * v.w;
#pragma unroll
    for (int off = 32; off; off >>= 1) ss += __shfl_xor(ss, off);
    term = sqrtf(ss);  // 0 for empty classes, matching reference
  }
  __shared__ float sp[4];
  if (lane == 0) sp[wave] = term;
  __syncthreads();
  if (threadIdx.x == 0) {
    atomicAdd(out, sp[0] + sp[1] + sp[2] + sp[3]);
    __threadfence();  // out-add visible before done-add
    const unsigned d = atomicAdd(done, 1u);
    if (d == gridDim.x - 1) {               // all other blocks' adds visible
      const float t = atomicAdd(out, 0.f);  // device-coherent read of total
      out[0] = 1.f - t / (float)B;
    }
  }
}

extern "C" void kernel_launch(void* const* d_in, const int* in_sizes, int n_in,
                              void* d_out, int out_size, void* d_ws, size_t ws_size,
                              hipStream_t stream) {
  const float* x      = (const float*)d_in[0];
  const int*   labels = (const int*)d_in[1];
  const int B = in_sizes[1];
  const int C = 1000;  // fixed by problem setup

  // ws layout: cnt[C] | done | cursors[C] | pr[B] int2 | sums[C*DIM] floats
  char* ws = (char*)d_ws;
  int*      cnt     = (int*)ws;                                  // C ints
  unsigned* done    = (unsigned*)(ws + (size_t)C * sizeof(int)); // 1 int
  int*      cursors = (int*)(ws + (size_t)(C + 1) * sizeof(int));
  size_t off = (((size_t)(2 * C + 1) * sizeof(int)) + 15) & ~(size_t)15;
  int2*  pr   = (int2*)(ws + off);
  off += (size_t)B * sizeof(int2);
  float* sums = (float*)(ws + off);

  k_init<<<2, 512, 0, stream>>>(cnt, C);  // zeroes cnt[0..C] (incl. done)
  k_count<<<NBC, 256, 0, stream>>>((const int4*)labels, cnt, sums, B / 4, C,
                                   C * DIM);
  k_scan<<<1, 1024, 0, stream>>>(cnt, cursors, (float*)d_out, C);
  k_permute<<<NBC, 256, 0, stream>>>(labels, cursors, pr, B);
  k_segsum<<<SSB, 256, 0, stream>>>(x, pr, sums, B);
  const int nblk = (C + 3) / 4;
  k_norm<<<nblk, 256, 0, stream>>>(sums, (float*)d_out, done, C, B);
}

// Round 7
// 385.388 us; speedup vs baseline: 1.1092x; 1.1052x over previous
//
#include <hip/hip_runtime.h>

// out = 1 - (1/B) * sum_c || sum_{b: label_b=c} x_b/||x_b|| ||
// Deterministic pipeline: per-block histogram -> batched scan (bases) ->
// LDS-cursor permutation (block-major, ascending within class) ->
// streaming segmented sum over class-sorted rows -> norms + fused final.

#define DIM 256       // feature dim (fixed by problem setup)
#define NB 64         // histogram / permutation blocks
#define SSB 2048      // segmented-sum blocks: 8192 waves = full occupancy

typedef float fx4 __attribute__((ext_vector_type(4)));

// ---------------------------------------------------------------------------
// K1: per-block label histogram (LDS-privatized, no global atomics); also
// zeroes the sums table so no separate memset dispatch is needed.
// ---------------------------------------------------------------------------
__global__ __launch_bounds__(256) void k_hist(const int* __restrict__ labels,
                                              int* __restrict__ hist,
                                              float* __restrict__ sums,
                                              int B, int C, int CD) {
  extern __shared__ int s_h[];  // C ints
  const int tid = threadIdx.x;
  for (int i = blockIdx.x * 256 + tid; i < CD; i += NB * 256) sums[i] = 0.f;
  for (int c = tid; c < C; c += 256) s_h[c] = 0;
  __syncthreads();
  const int chunk = (B + NB - 1) / NB;
  const int r0 = blockIdx.x * chunk;
  const int r1 = min(B, r0 + chunk);
  for (int i = r0 + tid; i < r1; i += 256) atomicAdd(&s_h[labels[i]], 1);
  __syncthreads();
  int* dst = hist + (size_t)blockIdx.x * C;
  for (int c = tid; c < C; c += 256) dst[c] = s_h[c];
}

// ---------------------------------------------------------------------------
// K2: single block. hist[b][c] -> bases[b][c] = class_offset[c] + prefix_b.
// All NB counts are loaded into registers first (independent loads in
// flight) so there are no serial global round-trips. Also zeroes out[0] and
// the done counter before k_norm.
// ---------------------------------------------------------------------------
__global__ __launch_bounds__(1024) void k_scan(int* __restrict__ hist,
                                               float* __restrict__ out,
                                               unsigned* __restrict__ done,
                                               int C) {
  __shared__ int s[2][1024];
  const int tid = threadIdx.x;
  if (tid == 0) { out[0] = 0.f; *done = 0u; }
  int h[NB];
  int total = 0;
  if (tid < C) {
#pragma unroll
    for (int b = 0; b < NB; ++b) h[b] = hist[(size_t)b * C + tid];  // batched
#pragma unroll
    for (int b = 0; b < NB; ++b) {  // register prefix over blocks
      const int t = h[b];
      h[b] = total;
      total += t;
    }
  }
  int cur = 0;
  s[0][tid] = total;
  __syncthreads();
  for (int d = 1; d < 1024; d <<= 1) {  // Hillis-Steele inclusive scan
    const int v = s[cur][tid] + (tid >= d ? s[cur][tid - d] : 0);
    s[1 - cur][tid] = v;
    __syncthreads();
    cur ^= 1;
  }
  const int exoff = s[cur][tid] - total;  // exclusive class offset
  if (tid < C) {
#pragma unroll
    for (int b = 0; b < NB; ++b) hist[(size_t)b * C + tid] = h[b] + exoff;
  }
}

// ---------------------------------------------------------------------------
// K3: counting-sort scatter via LDS cursors (deterministic block-major,
// ascending row order within each class segment).
// ---------------------------------------------------------------------------
__global__ __launch_bounds__(256) void k_permute(const int* __restrict__ labels,
                                                 const int* __restrict__ bases,
                                                 int2* __restrict__ pr,
                                                 int B, int C) {
  extern __shared__ int s_cur[];  // C ints
  const int tid = threadIdx.x;
  const int* bp = bases + (size_t)blockIdx.x * C;
  for (int c = tid; c < C; c += 256) s_cur[c] = bp[c];
  __syncthreads();
  const int chunk = (B + NB - 1) / NB;
  const int r0 = blockIdx.x * chunk;
  const int r1 = min(B, r0 + chunk);
  for (int i = r0 + tid; i < r1; i += 256) {
    const int l = labels[i];
    const int pos = atomicAdd(&s_cur[l], 1);
    pr[pos] = make_int2(i, l);
  }
}

// ---------------------------------------------------------------------------
// K4: streaming segmented sum over class-sorted rows. 8192 waves, 32 rows
// each, batches of 8 so 8 independent 1KB row loads are in flight per wave.
// ---------------------------------------------------------------------------
__device__ __forceinline__ void flush_acc(float* __restrict__ sums, int c,
                                          const fx4& a, int lane) {
  float* dst = sums + (size_t)c * DIM + lane * 4;
  atomicAdd(dst + 0, a.x);
  atomicAdd(dst + 1, a.y);
  atomicAdd(dst + 2, a.z);
  atomicAdd(dst + 3, a.w);
}

__global__ __launch_bounds__(256) void k_segsum(const float* __restrict__ x,
                                                const int2* __restrict__ pr,
                                                float* __restrict__ sums,
                                                int B) {
  const int lane = threadIdx.x & 63;
  const int wid = __builtin_amdgcn_readfirstlane(
      (blockIdx.x << 2) | (threadIdx.x >> 6));
  const int nw = SSB * 4;
  const int per = (B + nw - 1) / nw;  // 32 for B=262144
  const int r0 = wid * per;
  const int r1 = min(B, r0 + per);
  if (r0 >= r1) return;

  fx4 acc = {0.f, 0.f, 0.f, 0.f};
  int prev = -1;
  int rb = r0;

  for (; rb + 8 <= r1; rb += 8) {
    int2 e[8];
#pragma unroll
    for (int k = 0; k < 8; ++k) e[k] = pr[rb + k];  // wave-uniform
    fx4 v[8];
#pragma unroll
    for (int k = 0; k < 8; ++k)  // 8 independent 1KB coalesced loads
      v[k] = __builtin_nontemporal_load(
          (const fx4*)(x + (size_t)e[k].x * DIM) + lane);
    float ss[8];
#pragma unroll
    for (int k = 0; k < 8; ++k)
      ss[k] = v[k].x * v[k].x + v[k].y * v[k].y + v[k].z * v[k].z +
              v[k].w * v[k].w;
#pragma unroll
    for (int off = 32; off; off >>= 1) {  // 8 interleaved reduce chains
#pragma unroll
      for (int k = 0; k < 8; ++k) ss[k] += __shfl_xor(ss[k], off);
    }
#pragma unroll
    for (int k = 0; k < 8; ++k) {
      const float inv = 1.f / fmaxf(sqrtf(ss[k]), 1e-12f);
      const int lab = e[k].y;
      if (lab != prev) {  // wave-uniform (scalar) branch
        if (prev >= 0) flush_acc(sums, prev, acc, lane);
        acc = (fx4){0.f, 0.f, 0.f, 0.f};
        prev = lab;
      }
      acc.x += v[k].x * inv; acc.y += v[k].y * inv;
      acc.z += v[k].z * inv; acc.w += v[k].w * inv;
    }
  }
  for (; rb < r1; ++rb) {  // tail (unused when per % 8 == 0)
    const int2 e = pr[rb];
    const fx4 v = ((const fx4*)(x + (size_t)e.x * DIM))[lane];
    float ss = v.x * v.x + v.y * v.y + v.z * v.z + v.w * v.w;
#pragma unroll
    for (int off = 32; off; off >>= 1) ss += __shfl_xor(ss, off);
    const float inv = 1.f / fmaxf(sqrtf(ss), 1e-12f);
    if (e.y != prev) {
      if (prev >= 0) flush_acc(sums, prev, acc, lane);
      acc = (fx4){0.f, 0.f, 0.f, 0.f};
      prev = e.y;
    }
    acc.x += v.x * inv; acc.y += v.y * inv;
    acc.z += v.z * inv; acc.w += v.w * inv;
  }
  if (prev >= 0) flush_acc(sums, prev, acc, lane);
}

// ---------------------------------------------------------------------------
// K5: per-class norm, block-sum, one atomic per block into out[0]; the last
// block to finish (done-counter) applies the final 1 - T/B transform.
// ---------------------------------------------------------------------------
__global__ __launch_bounds__(256) void k_norm(const float* __restrict__ sums,
                                              float* __restrict__ out,
                                              unsigned* __restrict__ done,
                                              int C, int B) {
  const int wave = threadIdx.x >> 6;
  const int lane = threadIdx.x & 63;
  const int c = blockIdx.x * 4 + wave;
  float term = 0.f;
  if (c < C) {
    const fx4 v = ((const fx4*)(sums + (size_t)c * DIM))[lane];
    float ss = v.x * v.x + v.y * v.y + v.z * v.z + v.w * v.w;
#pragma unroll
    for (int off = 32; off; off >>= 1) ss += __shfl_xor(ss, off);
    term = sqrtf(ss);  // 0 for empty classes, matching reference
  }
  __shared__ float sp[4];
  if (lane == 0) sp[wave] = term;
  __syncthreads();
  if (threadIdx.x == 0) {
    atomicAdd(out, sp[0] + sp[1] + sp[2] + sp[3]);
    __threadfence();  // out-add visible before done-add
    const unsigned d = atomicAdd(done, 1u);
    if (d == gridDim.x - 1) {               // all other blocks' adds visible
      const float t = atomicAdd(out, 0.f);  // device-coherent read of total
      out[0] = 1.f - t / (float)B;
    }
  }
}

extern "C" void kernel_launch(void* const* d_in, const int* in_sizes, int n_in,
                              void* d_out, int out_size, void* d_ws, size_t ws_size,
                              hipStream_t stream) {
  const float* x      = (const float*)d_in[0];
  const int*   labels = (const int*)d_in[1];
  const int B = in_sizes[1];
  const int C = 1000;  // fixed by problem setup

  // ws layout: hist[NB*C] ints | done | pr[B] int2 | sums[C*DIM] floats
  char* ws = (char*)d_ws;
  int*      hist = (int*)ws;
  unsigned* done = (unsigned*)(ws + (size_t)NB * C * sizeof(int));
  size_t off = (((size_t)NB * C + 1) * sizeof(int) + 15) & ~(size_t)15;
  int2*  pr   = (int2*)(ws + off);
  off += (size_t)B * sizeof(int2);
  float* sums = (float*)(ws + off);

  const size_t lds_c = (size_t)C * sizeof(int);
  k_hist<<<NB, 256, lds_c, stream>>>(labels, hist, sums, B, C, C * DIM);
  k_scan<<<1, 1024, 0, stream>>>(hist, (float*)d_out, done, C);
  k_permute<<<NB, 256, lds_c, stream>>>(labels, hist, pr, B, C);
  k_segsum<<<SSB, 256, 0, stream>>>(x, pr, sums, B);
  const int nblk = (C + 3) / 4;
  k_norm<<<nblk, 256, 0, stream>>>(sums, (float*)d_out, done, C, B);
}

// Round 8
// 378.521 us; speedup vs baseline: 1.1294x; 1.0181x over previous
//
#include <hip/hip_runtime.h>

// out = 1 - (1/B) * sum_c || sum_{b: label_b=c} x_b/||x_b|| ||
// Deterministic pipeline: per-block histogram -> batched scan (bases +
// global class offsets) -> LDS-cursor permutation (row indices only,
// block-major ascending within class) -> software-pipelined streaming
// segmented sum (boundaries from offsets[], scalar walk) -> norms + final.

#define DIM 256       // feature dim (fixed by problem setup)
#define NB 64         // histogram / permutation blocks
#define SSB 2048      // segmented-sum blocks: 8192 waves

typedef float fx4 __attribute__((ext_vector_type(4)));

// ---------------------------------------------------------------------------
// K1: per-block label histogram (LDS-privatized, no global atomics); also
// zeroes the sums table so no separate memset dispatch is needed.
// ---------------------------------------------------------------------------
__global__ __launch_bounds__(256) void k_hist(const int* __restrict__ labels,
                                              int* __restrict__ hist,
                                              float* __restrict__ sums,
                                              int B, int C, int CD) {
  extern __shared__ int s_h[];  // C ints
  const int tid = threadIdx.x;
  for (int i = blockIdx.x * 256 + tid; i < CD; i += NB * 256) sums[i] = 0.f;
  for (int c = tid; c < C; c += 256) s_h[c] = 0;
  __syncthreads();
  const int chunk = (B + NB - 1) / NB;
  const int r0 = blockIdx.x * chunk;
  const int r1 = min(B, r0 + chunk);
  for (int i = r0 + tid; i < r1; i += 256) atomicAdd(&s_h[labels[i]], 1);
  __syncthreads();
  int* dst = hist + (size_t)blockIdx.x * C;
  for (int c = tid; c < C; c += 256) dst[c] = s_h[c];
}

// ---------------------------------------------------------------------------
// K2: single block. hist[b][c] -> bases[b][c] = class_offset[c] + prefix_b
// (batched register loads, no serial global round-trips). Also emits the
// global class offsets[0..C] and zeroes out[0] / done.
// ---------------------------------------------------------------------------
__global__ __launch_bounds__(1024) void k_scan(int* __restrict__ hist,
                                               int* __restrict__ offsets,
                                               float* __restrict__ out,
                                               unsigned* __restrict__ done,
                                               int C) {
  __shared__ int s[2][1024];
  const int tid = threadIdx.x;
  if (tid == 0) { out[0] = 0.f; *done = 0u; }
  int h[NB];
  int total = 0;
  if (tid < C) {
#pragma unroll
    for (int b = 0; b < NB; ++b) h[b] = hist[(size_t)b * C + tid];  // batched
#pragma unroll
    for (int b = 0; b < NB; ++b) {  // register prefix over blocks
      const int t = h[b];
      h[b] = total;
      total += t;
    }
  }
  int cur = 0;
  s[0][tid] = total;
  __syncthreads();
  for (int d = 1; d < 1024; d <<= 1) {  // Hillis-Steele inclusive scan
    const int v = s[cur][tid] + (tid >= d ? s[cur][tid - d] : 0);
    s[1 - cur][tid] = v;
    __syncthreads();
    cur ^= 1;
  }
  const int exoff = s[cur][tid] - total;  // exclusive class offset
  if (tid <= C) offsets[tid] = exoff;     // offsets[C] == B
  if (tid < C) {
#pragma unroll
    for (int b = 0; b < NB; ++b) hist[(size_t)b * C + tid] = h[b] + exoff;
  }
}

// ---------------------------------------------------------------------------
// K3: counting-sort scatter via LDS cursors (deterministic block-major,
// ascending row order within each class segment). Rows only — labels are
// implied by offsets[].
// ---------------------------------------------------------------------------
__global__ __launch_bounds__(256) void k_permute(const int* __restrict__ labels,
                                                 const int* __restrict__ bases,
                                                 int* __restrict__ rows,
                                                 int B, int C) {
  extern __shared__ int s_cur[];  // C ints
  const int tid = threadIdx.x;
  const int* bp = bases + (size_t)blockIdx.x * C;
  for (int c = tid; c < C; c += 256) s_cur[c] = bp[c];
  __syncthreads();
  const int chunk = (B + NB - 1) / NB;
  const int r0 = blockIdx.x * chunk;
  const int r1 = min(B, r0 + chunk);
  for (int i = r0 + tid; i < r1; i += 256) {
    const int l = labels[i];
    const int pos = atomicAdd(&s_cur[l], 1);
    rows[pos] = i;
  }
}

// ---------------------------------------------------------------------------
// K4: software-pipelined streaming segmented sum over class-sorted rows.
// Batch b+1's 8 row loads are issued BEFORE batch b is processed (double
// buffer), so 8KB/wave stays in flight. Class boundaries come from a scalar
// walk of offsets[] (uniform per wave) — no labels, no data-dependent
// branches around the loads.
// ---------------------------------------------------------------------------
__device__ __forceinline__ void flush_acc(float* __restrict__ sums, int c,
                                          const fx4& a, int lane) {
  float* dst = sums + (size_t)c * DIM + lane * 4;
  atomicAdd(dst + 0, a.x);
  atomicAdd(dst + 1, a.y);
  atomicAdd(dst + 2, a.z);
  atomicAdd(dst + 3, a.w);
}

__global__ __launch_bounds__(256) void k_segsum(const float* __restrict__ x,
                                                const int* __restrict__ rows,
                                                const int* __restrict__ offsets,
                                                float* __restrict__ sums,
                                                int B, int C) {
  const int lane = threadIdx.x & 63;
  const int wid = __builtin_amdgcn_readfirstlane(
      (blockIdx.x << 2) | (threadIdx.x >> 6));
  const int nw = SSB * 4;
  const int per = (B + nw - 1) / nw;  // 32 for B=262144
  const int r0 = wid * per;
  const int r1 = min(B, r0 + per);
  if (r0 >= r1) return;

  // binary search: c = largest class with offsets[c] <= r0 (wave-uniform)
  int lo = 0, hi = C;
  while (hi - lo > 1) {
    const int mid = (lo + hi) >> 1;
    if (offsets[mid] <= r0) lo = mid; else hi = mid;
  }
  int c = lo;
  int nextOff = offsets[c + 1];

  fx4 acc = {0.f, 0.f, 0.f, 0.f};
  int rb = r0;

  if (rb + 8 <= r1) {
    fx4 v[8];
#pragma unroll
    for (int k = 0; k < 8; ++k)  // prime the pipeline
      v[k] = __builtin_nontemporal_load(
          (const fx4*)(x + (size_t)rows[rb + k] * DIM) + lane);
    for (; rb + 8 <= r1; rb += 8) {
      const bool more = (rb + 16 <= r1);
      fx4 w[8];
      if (more) {
#pragma unroll
        for (int k = 0; k < 8; ++k)  // prefetch next batch (stays in flight)
          w[k] = __builtin_nontemporal_load(
              (const fx4*)(x + (size_t)rows[rb + 8 + k] * DIM) + lane);
      }
      float ss[8];
#pragma unroll
      for (int k = 0; k < 8; ++k)
        ss[k] = v[k].x * v[k].x + v[k].y * v[k].y + v[k].z * v[k].z +
                v[k].w * v[k].w;
#pragma unroll
      for (int off = 32; off; off >>= 1) {  // 8 interleaved reduce chains
#pragma unroll
        for (int k = 0; k < 8; ++k) ss[k] += __shfl_xor(ss[k], off);
      }
#pragma unroll
      for (int k = 0; k < 8; ++k) {
        const float inv = 1.f / fmaxf(sqrtf(ss[k]), 1e-12f);
        const int p = rb + k;
        if (p >= nextOff) {  // wave-uniform scalar boundary walk
          flush_acc(sums, c, acc, lane);
          acc = (fx4){0.f, 0.f, 0.f, 0.f};
          do { ++c; } while (offsets[c + 1] <= p);
          nextOff = offsets[c + 1];
        }
        acc.x += v[k].x * inv; acc.y += v[k].y * inv;
        acc.z += v[k].z * inv; acc.w += v[k].w * inv;
      }
      if (more) {
#pragma unroll
        for (int k = 0; k < 8; ++k) v[k] = w[k];
      }
    }
  }
  for (; rb < r1; ++rb) {  // tail (unused when per % 8 == 0)
    const fx4 v = ((const fx4*)(x + (size_t)rows[rb] * DIM))[lane];
    float ss = v.x * v.x + v.y * v.y + v.z * v.z + v.w * v.w;
#pragma unroll
    for (int off = 32; off; off >>= 1) ss += __shfl_xor(ss, off);
    const float inv = 1.f / fmaxf(sqrtf(ss), 1e-12f);
    if (rb >= nextOff) {
      flush_acc(sums, c, acc, lane);
      acc = (fx4){0.f, 0.f, 0.f, 0.f};
      do { ++c; } while (offsets[c + 1] <= rb);
      nextOff = offsets[c + 1];
    }
    acc.x += v.x * inv; acc.y += v.y * inv;
    acc.z += v.z * inv; acc.w += v.w * inv;
  }
  flush_acc(sums, c, acc, lane);
}

// ---------------------------------------------------------------------------
// K5: per-class norm, block-sum, one atomic per block into out[0]; the last
// block to finish (done-counter) applies the final 1 - T/B transform.
// ---------------------------------------------------------------------------
__global__ __launch_bounds__(256) void k_norm(const float* __restrict__ sums,
                                              float* __restrict__ out,
                                              unsigned* __restrict__ done,
                                              int C, int B) {
  const int wave = threadIdx.x >> 6;
  const int lane = threadIdx.x & 63;
  const int c = blockIdx.x * 4 + wave;
  float term = 0.f;
  if (c < C) {
    const fx4 v = ((const fx4*)(sums + (size_t)c * DIM))[lane];
    float ss = v.x * v.x + v.y * v.y + v.z * v.z + v.w * v.w;
#pragma unroll
    for (int off = 32; off; off >>= 1) ss += __shfl_xor(ss, off);
    term = sqrtf(ss);  // 0 for empty classes, matching reference
  }
  __shared__ float sp[4];
  if (lane == 0) sp[wave] = term;
  __syncthreads();
  if (threadIdx.x == 0) {
    atomicAdd(out, sp[0] + sp[1] + sp[2] + sp[3]);
    __threadfence();  // out-add visible before done-add
    const unsigned d = atomicAdd(done, 1u);
    if (d == gridDim.x - 1) {               // all other blocks' adds visible
      const float t = atomicAdd(out, 0.f);  // device-coherent read of total
      out[0] = 1.f - t / (float)B;
    }
  }
}

extern "C" void kernel_launch(void* const* d_in, const int* in_sizes, int n_in,
                              void* d_out, int out_size, void* d_ws, size_t ws_size,
                              hipStream_t stream) {
  const float* x      = (const float*)d_in[0];
  const int*   labels = (const int*)d_in[1];
  const int B = in_sizes[1];
  const int C = 1000;  // fixed by problem setup

  // ws: hist[NB*C] | offsets[C+1] | done | rows[B] | sums[C*DIM]
  char* ws = (char*)d_ws;
  int* hist = (int*)ws;
  size_t off = (size_t)NB * C * sizeof(int);
  int* offsets = (int*)(ws + off);
  off += (size_t)(C + 1) * sizeof(int);
  unsigned* done = (unsigned*)(ws + off);
  off = (off + sizeof(int) + 15) & ~(size_t)15;
  int* rows = (int*)(ws + off);
  off += (size_t)B * sizeof(int);
  float* sums = (float*)(ws + off);

  const size_t lds_c = (size_t)C * sizeof(int);
  k_hist<<<NB, 256, lds_c, stream>>>(labels, hist, sums, B, C, C * DIM);
  k_scan<<<1, 1024, 0, stream>>>(hist, offsets, (float*)d_out, done, C);
  k_permute<<<NB, 256, lds_c, stream>>>(labels, hist, rows, B, C);
  k_segsum<<<SSB, 256, 0, stream>>>(x, rows, offsets, sums, B, C);
  const int nblk = (C + 3) / 4;
  k_norm<<<nblk, 256, 0, stream>>>(sums, (float*)d_out, done, C, B);
}